// Round 6
// baseline (318.566 us; speedup 1.0000x reference)
//
#include <hip/hip_runtime.h>
#include <hip/hip_bf16.h>
#include <math.h>

typedef __attribute__((ext_vector_type(8))) short bf16x8;
typedef __attribute__((ext_vector_type(4))) float f32x4;

__device__ inline unsigned short f2bf(float f) {
    return __builtin_bit_cast(unsigned short, __float2bfloat16(f));
}
__device__ inline float bf2f(unsigned short u) {
    return __bfloat162float(__builtin_bit_cast(__hip_bfloat16, u));
}
__device__ inline bf16x8 cvt8(float4 a, float4 b) {
    bf16x8 r;
    r[0]=(short)f2bf(a.x); r[1]=(short)f2bf(a.y); r[2]=(short)f2bf(a.z); r[3]=(short)f2bf(a.w);
    r[4]=(short)f2bf(b.x); r[5]=(short)f2bf(b.y); r[6]=(short)f2bf(b.z); r[7]=(short)f2bf(b.w);
    return r;
}
__device__ inline void split8(float4 a, float4 b, bf16x8& hi, bf16x8& lo) {
    float f[8] = {a.x,a.y,a.z,a.w,b.x,b.y,b.z,b.w};
    #pragma unroll
    for (int i = 0; i < 8; ++i) {
        unsigned short h = f2bf(f[i]);
        hi[i] = (short)h;
        lo[i] = (short)f2bf(f[i] - bf2f(h));
    }
}

// LDS map (f32 idx units; total 7408 fl = 29632 B):
//  xv   f32 [25][65]     @0     whole kernel (residual + xvT source)
//  ynh  u16 [25][64]swz  @1628  p1-2 (frag reads rows>=25 spill -> garbage, discarded)
//  ynl  u16 [25][64]swz  @2428  p1-2
//  res  f32 [64][25]     @1628  p6+  (overlays yn, dead)
//  qk_h u16 [25][56]     @3228  p2-3 (spill reads ok)
//  qk_l u16 [25][56]     @3928  p2-3
//  A_bf u16 [75][40]     @4628  p3-5 (frag rows 75..79 spill into xvT -> discarded)
//  zA   u16 [25][200]    @4628  p5b+ (overlays A_bf after reg-defer barrier)
//  xvT  u16 [64][40]     @6128  p2-5
#define LDS_FLOATS 7408

__global__ __launch_bounds__(256, 4)
void agcn_fused_kernel(const float* __restrict__ x,
                       const float* __restrict__ PA,
                       const float* __restrict__ ln_g, const float* __restrict__ ln_b,
                       const float* __restrict__ Wqk, const float* __restrict__ bqk,
                       const float* __restrict__ conv_w, const float* __restrict__ conv_b,
                       const float* __restrict__ bn_g, const float* __restrict__ bn_b,
                       const float* __restrict__ bn_m, const float* __restrict__ bn_v,
                       float* __restrict__ out)
{
    __shared__ float lds[LDS_FLOATS];
    float* xv = lds;                                      // [25][65]
    unsigned short* ynh  = (unsigned short*)(lds + 1628);
    unsigned short* ynl  = (unsigned short*)(lds + 2428);
    float* res = lds + 1628;                              // [64][25]
    unsigned short* qk_h = (unsigned short*)(lds + 3228); // [25][56]
    unsigned short* qk_l = (unsigned short*)(lds + 3928);
    unsigned short* A_bf = (unsigned short*)(lds + 4628); // [75][40]
    unsigned short* zA   = (unsigned short*)(lds + 4628); // [25][200]
    unsigned short* xvT  = (unsigned short*)(lds + 6128); // [64][40]

    const int bid = blockIdx.x;
    const int n = bid >> 7, t = bid & 127;
    const int tid = threadIdx.x;
    const int lane = tid & 63, w = tid >> 6;
    const int g = lane >> 4, l15 = lane & 15;

    // ================= prologue: issue ALL param loads =================
    const int o = 16 * w + l15;
    float4 cw_f[12];
    #pragma unroll
    for (int kt = 0; kt < 6; ++kt) {
        const float* wp = &conv_w[(kt >> 1) * 4096 + o * 64 + (kt & 1) * 32 + 8 * g];
        cw_f[2*kt]   = *(const float4*)wp;
        cw_f[2*kt+1] = *(const float4*)(wp + 4);
    }
    float4 wq_f[4];
    float bq = 0.f;
    f32x4 pa[2][2] = {{{0,0,0,0},{0,0,0,0}},{{0,0,0,0},{0,0,0,0}}};
    if (w < 3) {
        const int j = 16 * w + l15;
        #pragma unroll
        for (int ks = 0; ks < 2; ++ks) {
            const float* wp = &Wqk[j * 64 + ks * 32 + 8 * g];
            wq_f[2*ks]   = *(const float4*)wp;
            wq_f[2*ks+1] = *(const float4*)(wp + 4);
        }
        bq = bqk[j];
        // PA fragments for in-reg softmax (h = w): i = 16mt+4g+reg, jcol = 16jt+l15
        #pragma unroll
        for (int mt = 0; mt < 2; ++mt)
            #pragma unroll
            for (int jt = 0; jt < 2; ++jt)
                #pragma unroll
                for (int reg = 0; reg < 4; ++reg) {
                    int ii = 16*mt + 4*g + reg, jj = 16*jt + l15;
                    if (ii < 25 && jj < 25)
                        pa[mt][jt][reg] = PA[w * 625 + ii * 25 + jj];
                }
    }

    // ---- phase 0: stage x tile ----
    const float* xbase = x + (size_t)n * 204800 + t * 25;
    for (int idx = tid; idx < 1600; idx += 256) {
        int c = idx / 25, v = idx - c * 25;
        xv[v * 65 + c] = xbase[c * 3200 + v];
    }

    bf16x8 cw[6];
    #pragma unroll
    for (int kt = 0; kt < 6; ++kt) cw[kt] = cvt8(cw_f[2*kt], cw_f[2*kt+1]);
    bf16x8 wqh[2], wql[2];
    if (w < 3) {
        #pragma unroll
        for (int ks = 0; ks < 2; ++ks) split8(wq_f[2*ks], wq_f[2*ks+1], wqh[ks], wql[ks]);
    }
    __syncthreads();

    // ---- phase 1: LayerNorm -> yn hi/lo (bf16, swizzled) ----
    {
        float lg = ln_g[lane], lb = ln_b[lane];
        for (int v = w; v < 25; v += 4) {
            float val = xv[v * 65 + lane];
            float s = val;
            for (int off = 32; off; off >>= 1) s += __shfl_xor(s, off);
            float mu = s * (1.0f / 64.0f);
            float d = val - mu;
            float s2 = d * d;
            for (int off = 32; off; off >>= 1) s2 += __shfl_xor(s2, off);
            float rstd = rsqrtf(s2 * (1.0f / 64.0f) + 1e-5f);
            float y = d * rstd * lg + lb;
            unsigned short hh = f2bf(y);
            unsigned short ll = f2bf(y - bf2f(hh));
            int idx = (v * 64 + lane) ^ ((v & 7) << 3);
            ynh[idx] = hh;
            ynl[idx] = ll;
        }
    }
    __syncthreads();

    // ---- phase 2: qk MFMA (waves 0-2) -> qk hi/lo; wave 3 builds xvT ----
    if (w < 3) {
        const int j = 16 * w + l15;
        #pragma unroll
        for (int mt = 0; mt < 2; ++mt) {
            f32x4 acc = {bq, bq, bq, bq};
            #pragma unroll
            for (int ks = 0; ks < 2; ++ks) {
                int row = 16 * mt + l15;
                int idx = (row * 64 + ks * 32 + 8 * g) ^ ((row & 7) << 3);
                bf16x8 ah = *(bf16x8*)&ynh[idx];
                bf16x8 al = *(bf16x8*)&ynl[idx];
                acc = __builtin_amdgcn_mfma_f32_16x16x32_bf16(al, wqh[ks], acc, 0, 0, 0);
                acc = __builtin_amdgcn_mfma_f32_16x16x32_bf16(ah, wql[ks], acc, 0, 0, 0);
                acc = __builtin_amdgcn_mfma_f32_16x16x32_bf16(ah, wqh[ks], acc, 0, 0, 0);
            }
            #pragma unroll
            for (int reg = 0; reg < 4; ++reg) {
                int v = 16 * mt + 4 * g + reg;
                if (v < 25) {
                    float q = acc[reg];
                    unsigned short hh = f2bf(q);
                    qk_h[v * 56 + j] = hh;
                    qk_l[v * 56 + j] = f2bf(q - bf2f(hh));
                }
            }
        }
    } else {
        for (int idx = lane; idx < 2560; idx += 64) {
            int c = idx / 40, jj = idx - c * 40;
            xvT[idx] = f2bf(jj < 25 ? xv[jj * 65 + c] : 0.f);
        }
    }
    __syncthreads();

    // ---- phase 3: dots MFMA + in-reg softmax*PA -> A_bf (waves 0-2, h=w) ----
    if (w < 3) {
        const int h = w;
        const bf16x8 zz = {0,0,0,0,0,0,0,0};
        bf16x8 qhf[2], qlf[2], khf[2], klf[2];
        #pragma unroll
        for (int mt = 0; mt < 2; ++mt) {
            int row = 16 * mt + l15;
            bf16x8 a = *(bf16x8*)&qk_h[row * 56 + 8 * h];
            bf16x8 b = *(bf16x8*)&qk_l[row * 56 + 8 * h];
            qhf[mt] = (g == 0) ? a : zz;     // K=32 pad: d>=8 must be zero
            qlf[mt] = (g == 0) ? b : zz;
        }
        #pragma unroll
        for (int jt = 0; jt < 2; ++jt) {
            int row = 16 * jt + l15;
            bf16x8 a = *(bf16x8*)&qk_h[row * 56 + 24 + 8 * h];
            bf16x8 b = *(bf16x8*)&qk_l[row * 56 + 24 + 8 * h];
            khf[jt] = (g == 0) ? a : zz;
            klf[jt] = (g == 0) ? b : zz;
        }
        f32x4 dacc[2][2];
        #pragma unroll
        for (int mt = 0; mt < 2; ++mt)
            #pragma unroll
            for (int jt = 0; jt < 2; ++jt) {
                f32x4 a = {0.f, 0.f, 0.f, 0.f};
                a = __builtin_amdgcn_mfma_f32_16x16x32_bf16(qlf[mt], khf[jt], a, 0, 0, 0);
                a = __builtin_amdgcn_mfma_f32_16x16x32_bf16(qhf[mt], klf[jt], a, 0, 0, 0);
                a = __builtin_amdgcn_mfma_f32_16x16x32_bf16(qhf[mt], khf[jt], a, 0, 0, 0);
                dacc[mt][jt] = a;
            }
        const float SC = 0.35355339059327373f;
        #pragma unroll
        for (int mt = 0; mt < 2; ++mt) {
            #pragma unroll
            for (int reg = 0; reg < 4; ++reg) {
                float v0 = dacc[mt][0][reg] * SC;
                float v1 = dacc[mt][1][reg] * SC;
                float m = fmaxf(v0, (l15 < 9) ? v1 : -3.0e38f);
                m = fmaxf(m, __shfl_xor(m, 1));
                m = fmaxf(m, __shfl_xor(m, 2));
                m = fmaxf(m, __shfl_xor(m, 4));
                m = fmaxf(m, __shfl_xor(m, 8));
                float e0 = __expf(v0 - m);
                float e1 = (l15 < 9) ? __expf(v1 - m) : 0.f;
                float s = e0 + e1;
                s += __shfl_xor(s, 1);
                s += __shfl_xor(s, 2);
                s += __shfl_xor(s, 4);
                s += __shfl_xor(s, 8);
                float inv = 1.0f / s;
                int i = 16 * mt + 4 * g + reg;
                if (i < 25) {
                    unsigned short* rp = &A_bf[(h * 25 + i) * 40];
                    rp[l15] = f2bf(e0 * inv * pa[mt][0][reg]);
                    rp[16 + l15] = (l15 < 9) ? f2bf(e1 * inv * pa[mt][1][reg])
                                             : (unsigned short)0;
                }
            }
        }
    }
    __syncthreads();

    // ---- phase 5: z MFMA -> regs (zA write deferred past barrier) ----
    f32x4 zacc[5];
    {
        bf16x8 bfrag = *(bf16x8*)&xvT[(16 * w + l15) * 40 + 8 * g];
        #pragma unroll
        for (int mt = 0; mt < 5; ++mt) {
            bf16x8 afrag = *(bf16x8*)&A_bf[(16 * mt + l15) * 40 + 8 * g];
            f32x4 a = {0.f, 0.f, 0.f, 0.f};
            zacc[mt] = __builtin_amdgcn_mfma_f32_16x16x32_bf16(afrag, bfrag, a, 0, 0, 0);
        }
    }
    __syncthreads();   // p5 frag reads drained; A_bf dead

    #pragma unroll
    for (int mt = 0; mt < 5; ++mt) {
        #pragma unroll
        for (int reg = 0; reg < 4; ++reg) {
            int r = 16 * mt + 4 * g + reg;
            if (r < 75) {
                int h = r / 25, i = r - h * 25;
                zA[i * 200 + h * 64 + 16 * w + l15] = f2bf(zacc[mt][reg]);
            }
        }
    }
    __syncthreads();

    // ---- phase 6: conv MFMA + BN + residual + ReLU -> res ----
    {
        float bg = bn_g[o], bv = bn_v[o], bb = bn_b[o], bm = bn_m[o];
        float cb = conv_b[o] + conv_b[64 + o] + conv_b[128 + o];

        const int r1 = (16 + l15 < 25) ? (16 + l15) : 0;
        f32x4 acc0 = {0.f, 0.f, 0.f, 0.f}, acc1 = {0.f, 0.f, 0.f, 0.f};
        #pragma unroll
        for (int kt = 0; kt < 6; ++kt) {
            bf16x8 a0 = *(bf16x8*)&zA[l15 * 200 + 32 * kt + 8 * g];
            bf16x8 a1 = *(bf16x8*)&zA[r1 * 200 + 32 * kt + 8 * g];
            acc0 = __builtin_amdgcn_mfma_f32_16x16x32_bf16(a0, cw[kt], acc0, 0, 0, 0);
            acc1 = __builtin_amdgcn_mfma_f32_16x16x32_bf16(a1, cw[kt], acc1, 0, 0, 0);
        }
        float sc = bg * rsqrtf(bv + 1e-5f);
        float bi = cb * sc + bb - bm * sc;
        #pragma unroll
        for (int reg = 0; reg < 4; ++reg) {
            int v = 4 * g + reg;
            float val = acc0[reg] * sc + bi + xv[v * 65 + o];
            res[o * 25 + v] = fmaxf(val, 0.f);
        }
        #pragma unroll
        for (int reg = 0; reg < 4; ++reg) {
            int v = 16 + 4 * g + reg;
            if (v < 25) {
                float val = acc1[reg] * sc + bi + xv[v * 65 + o];
                res[o * 25 + v] = fmaxf(val, 0.f);
            }
        }
    }
    __syncthreads();

    // ---- coalesced store ----
    {
        float* ob = out + (size_t)n * 204800 + t * 25;
        for (int idx = tid; idx < 1600; idx += 256) {
            int c = idx / 25, v = idx - c * 25;
            ob[c * 3200 + v] = res[idx];
        }
    }
}

extern "C" void kernel_launch(void* const* d_in, const int* in_sizes, int n_in,
                              void* d_out, int out_size, void* d_ws, size_t ws_size,
                              hipStream_t stream) {
    const float* x      = (const float*)d_in[0];
    const float* PA     = (const float*)d_in[1];
    const float* ln_g   = (const float*)d_in[2];
    const float* ln_b   = (const float*)d_in[3];
    const float* Wqk    = (const float*)d_in[4];
    const float* bqk    = (const float*)d_in[5];
    const float* conv_w = (const float*)d_in[6];
    const float* conv_b = (const float*)d_in[7];
    const float* bn_g   = (const float*)d_in[8];
    const float* bn_b   = (const float*)d_in[9];
    const float* bn_m   = (const float*)d_in[10];
    const float* bn_v   = (const float*)d_in[11];
    float* outp = (float*)d_out;

    agcn_fused_kernel<<<dim3(128 * 128), dim3(256), 0, stream>>>(
        x, PA, ln_g, ln_b, Wqk, bqk, conv_w, conv_b,
        bn_g, bn_b, bn_m, bn_v, outp);
}